// Round 2
// baseline (533.019 us; speedup 1.0000x reference)
//
#include <hip/hip_runtime.h>
#include <hip/hip_bf16.h>

// Problem constants (match reference setup_inputs)
#define BB 8
#define HH 1024
#define EE 512
#define VV 32000
#define TT 100
#define KV 1536   // H+E
#define KK 2560   // 2H+E

// ---------------------------------------------------------------------------
// Kernel 1: e_v for all (b,w). No LDS staging: x_v (48 KB) is L2-resident and
// re-read from global. Each wave computes 4 W_V rows x 8 batches (32 dots,
// split-K over 64 lanes). Cross-lane reduction via halving exchange:
// 32 shuffles total instead of a 192-shuffle full butterfly.
// Writes p = exp(tanh(e_v)) for every (b,w) plus per-block per-b partials.
// ---------------------------------------------------------------------------
__global__ __launch_bounds__(256) void ev_kernel(
    const float* __restrict__ output, const float* __restrict__ input_step,
    const float* __restrict__ W_V, const float* __restrict__ b_V,
    float* __restrict__ d_out, float* __restrict__ blocksums) {
  __shared__ float wavesums[4][8];

  const int tid = threadIdx.x;
  const int wave = tid >> 6;
  const int lane = tid & 63;
  const int w0 = blockIdx.x * 16 + wave * 4;       // 4 rows per wave

  float v[32];                                     // v[r*8+b]
#pragma unroll
  for (int i = 0; i < 32; ++i) v[i] = 0.f;

#pragma unroll 2
  for (int jg = 0; jg < 6; ++jg) {
    const int off = jg * 256 + lane * 4;           // float offset into x_v row
    float4 wv0 = *(const float4*)(W_V + (size_t)(w0 + 0) * KV + off);
    float4 wv1 = *(const float4*)(W_V + (size_t)(w0 + 1) * KV + off);
    float4 wv2 = *(const float4*)(W_V + (size_t)(w0 + 2) * KV + off);
    float4 wv3 = *(const float4*)(W_V + (size_t)(w0 + 3) * KV + off);
    const float* xb;
    int stride;
    if (jg < 4) { xb = output + off;          stride = HH; }
    else        { xb = input_step + off - HH; stride = EE; }
#pragma unroll
    for (int b = 0; b < 8; ++b) {
      float4 x = *(const float4*)(xb + b * stride);
      v[0 * 8 + b] = fmaf(wv0.w, x.w, fmaf(wv0.z, x.z, fmaf(wv0.y, x.y, fmaf(wv0.x, x.x, v[0 * 8 + b]))));
      v[1 * 8 + b] = fmaf(wv1.w, x.w, fmaf(wv1.z, x.z, fmaf(wv1.y, x.y, fmaf(wv1.x, x.x, v[1 * 8 + b]))));
      v[2 * 8 + b] = fmaf(wv2.w, x.w, fmaf(wv2.z, x.z, fmaf(wv2.y, x.y, fmaf(wv2.x, x.x, v[2 * 8 + b]))));
      v[3 * 8 + b] = fmaf(wv3.w, x.w, fmaf(wv3.z, x.z, fmaf(wv3.y, x.y, fmaf(wv3.x, x.x, v[3 * 8 + b]))));
    }
  }

  // Halving exchange-reduce: 32 values x 64 lanes -> 1 value per lane.
  // After 5 steps + final xor32, lane L holds total[j], j = bitrev5(L & 31).
#pragma unroll
  for (int step = 0; step < 5; ++step) {
    const int m = 1 << step;
    const int half = 16 >> step;                   // 16,8,4,2,1
    const bool upper = (lane & m) != 0;
#pragma unroll
    for (int i = 0; i < half; ++i) {
      float send = upper ? v[i] : v[i + half];
      float keep = upper ? v[i + half] : v[i];
      v[i] = keep + __shfl_xor(send, m, 64);
    }
  }
  v[0] += __shfl_xor(v[0], 32, 64);

  const int j = ((lane & 1) << 4) | ((lane & 2) << 2) | (lane & 4) |
                ((lane & 8) >> 2) | ((lane & 16) >> 4);
  float p = 0.f;
  if (lane < 32) {
    const int r = j >> 3;
    const int b = j & 7;
    const int w = w0 + r;
    float ev = v[0] + b_V[w];
    p = expf(tanhf(ev));                           // |tanh| <= 1: no max trick needed
    d_out[(size_t)b * VV + w] = p;
  }
  // per-b partial sums: fold the r bits (lane bits 0,1); upper half is 0
  p += __shfl_xor(p, 1, 64);
  p += __shfl_xor(p, 2, 64);
  if ((lane & 35) == 0) {                          // lanes 0,4,...,28: distinct b
    wavesums[wave][j & 7] = p;
  }
  __syncthreads();
  if (tid < 8) {
    blocksums[(size_t)blockIdx.x * 8 + tid] =
        wavesums[0][tid] + wavesums[1][tid] + wavesums[2][tid] + wavesums[3][tid];
  }
}

// ---------------------------------------------------------------------------
// Kernel 2: topic corrections. One wave per (b,t). Lane-parallel dedup/count
// scan (2 strided iters + shuffle reduce). First-occurrence waves compute
// e_k = x_k . W_K[w] + b_K[w], p = exp(tanh(k*e_k)), overwrite d_out[b,w],
// record delta = p_new - p_old for the softmax sum.
// ---------------------------------------------------------------------------
__global__ __launch_bounds__(256) void topic_kernel(
    const float* __restrict__ output, const float* __restrict__ input_step,
    const float* __restrict__ context, const int* __restrict__ topic_idx,
    const float* __restrict__ W_K, const float* __restrict__ b_K,
    float* __restrict__ d_out, float* __restrict__ topic_delta) {
  const int wave = threadIdx.x >> 6;
  const int lane = threadIdx.x & 63;
  const int task = blockIdx.x * 4 + wave;          // < 800
  const int b = task / TT;
  const int t = task - b * TT;
  const int w = topic_idx[b * TT + t];

  int k = 0, first = TT;
  for (int t2 = lane; t2 < TT; t2 += 64) {
    int w2 = topic_idx[b * TT + t2];
    if (w2 == w) { ++k; first = min(first, t2); }
  }
#pragma unroll
  for (int off = 32; off; off >>= 1) {
    k += __shfl_xor(k, off, 64);
    first = min(first, __shfl_xor(first, off, 64));
  }
  const bool valid = (w != 0) && (first == t);     // dedup: first occurrence
  if (!valid) {
    if (lane == 0) topic_delta[task] = 0.f;
    return;
  }

  float s = 0.f;
#pragma unroll
  for (int i = 0; i < 10; ++i) {
    const int j = i * 256 + lane * 4;
    float4 wk = *(const float4*)(W_K + (size_t)w * KK + j);
    const float* xs;
    if (j < HH)            xs = output + b * HH + j;
    else if (j < HH + EE)  xs = input_step + b * EE + (j - HH);
    else                   xs = context + b * HH + (j - HH - EE);
    float4 x = *(const float4*)xs;
    s = fmaf(wk.w, x.w, fmaf(wk.z, x.z, fmaf(wk.y, x.y, fmaf(wk.x, x.x, s))));
  }
#pragma unroll
  for (int off = 32; off; off >>= 1) s += __shfl_xor(s, off, 64);

  if (lane == 0) {
    float p = expf(tanhf((float)k * (s + b_K[w])));
    float pold = d_out[(size_t)b * VV + w];
    d_out[(size_t)b * VV + w] = p;
    topic_delta[task] = p - pold;
  }
}

// ---------------------------------------------------------------------------
// Kernel 3: sums[b] = sum(blocksums[:,b]) + sum(topic_delta[b,:])
// ---------------------------------------------------------------------------
__global__ __launch_bounds__(256) void reduce_kernel(
    const float* __restrict__ blocksums, const float* __restrict__ topic_delta,
    float* __restrict__ sums, int nblocks) {
  const int b = blockIdx.x;
  const int tid = threadIdx.x;
  float s = 0.f;
  for (int i = tid; i < nblocks; i += 256) s += blocksums[(size_t)i * 8 + b];
  if (tid < TT) s += topic_delta[b * TT + tid];
  __shared__ float red[4];
#pragma unroll
  for (int off = 32; off; off >>= 1) s += __shfl_xor(s, off, 64);
  if ((tid & 63) == 0) red[tid >> 6] = s;
  __syncthreads();
  if (tid == 0) sums[b] = red[0] + red[1] + red[2] + red[3];
}

// ---------------------------------------------------------------------------
// Kernel 4: normalize in place (float4)
// ---------------------------------------------------------------------------
__global__ __launch_bounds__(256) void norm_kernel(
    float* __restrict__ d_out, const float* __restrict__ sums) {
  const int i = blockIdx.x * 256 + threadIdx.x;    // float4 index, 64000 total
  const int b = i / (VV / 4);                      // /8000
  float4 v = *((const float4*)d_out + i);
  const float s = sums[b];
  v.x /= s; v.y /= s; v.z /= s; v.w /= s;
  *((float4*)d_out + i) = v;
}

extern "C" void kernel_launch(void* const* d_in, const int* in_sizes, int n_in,
                              void* d_out, int out_size, void* d_ws, size_t ws_size,
                              hipStream_t stream) {
  const float* output     = (const float*)d_in[0];
  const float* input_step = (const float*)d_in[1];
  const float* context    = (const float*)d_in[2];
  const int*   topic_idx  = (const int*)d_in[3];
  // d_in[4] = topic_length scalar (100), unused: hardcoded
  const float* W_V = (const float*)d_in[5];
  const float* b_V = (const float*)d_in[6];
  const float* W_K = (const float*)d_in[7];
  const float* b_K = (const float*)d_in[8];
  float* out = (float*)d_out;

  float* ws_f        = (float*)d_ws;
  float* topic_delta = ws_f;                 // 800 floats
  float* blocksums   = ws_f + 800;           // 2000*8 floats
  float* sums        = ws_f + 800 + 16000;   // 8 floats

  const int nblocks = VV / 16;               // 2000: 16 rows (4 waves x 4) per block

  ev_kernel<<<nblocks, 256, 0, stream>>>(output, input_step, W_V, b_V, out, blocksums);
  topic_kernel<<<(BB * TT) / 4, 256, 0, stream>>>(output, input_step, context,
                                                  topic_idx, W_K, b_K, out, topic_delta);
  reduce_kernel<<<BB, 256, 0, stream>>>(blocksums, topic_delta, sums, nblocks);
  norm_kernel<<<(VV / 4) * BB / 256, 256, 0, stream>>>(out, sums);
}